// Round 9
// baseline (13560.103 us; speedup 1.0000x reference)
//
#include <hip/hip_runtime.h>

#define B_  256
#define T_  512
#define F_  64
#define H_  1024
#define TL_ 64

typedef _Float16 half8 __attribute__((ext_vector_type(8)));
typedef float   floatx4 __attribute__((ext_vector_type(4)));
typedef unsigned long long ull;

#define MFMA(a, b, c) __builtin_amdgcn_mfma_f32_16x16x32_f16(a, b, c, 0, 0, 0)

// ws layout (bytes)
#define WF_E   0UL          // W_hh enc fragments: 3*64*32 chunks * 1024B
#define WF_D   6291456UL    // W_hh dec fragments
#define WF_I   12582912UL   // W_ih enc fragments: 3*64*2 chunks * 1024B
#define HP     12976128UL   // h planes: [2 parity][hi,lo]; plane = 512KB
#define PB     15073280UL   // fc partials: [2][64 jg][256 rows] f32
#define BARS   15204352UL   // 16 group counters, 128B apart
#define HPLANE 524288UL
// h plane layout (fragment-major): [rg 16][kb 32][lane 64][16B]; slab for
// row-group rg = 32KB/plane; block (rg,cb2) owns the contiguous 4KB at
// rg*32768 + cb2*4096 (cols cb2*128..+128 == kb cb2*4..cb2*4+3).

// LLC-coherent scalar atomics (sc0 sc1: bypass L1/L2, coherent at IF).
__device__ __forceinline__ void sta8(void* p, ull v) {
  __hip_atomic_store((ull*)p, v, __ATOMIC_RELAXED, __HIP_MEMORY_SCOPE_AGENT);
}
__device__ __forceinline__ float lda4f(const float* p) {
  return __hip_atomic_load(p, __ATOMIC_RELAXED, __HIP_MEMORY_SCOPE_AGENT);
}

// ---------------------------------------------------------------------------
// Setup: W_hh (enc,dec) and W_ih (enc) fp32 -> fp16 MFMA-B fragment layout.
// B-frag 16x16x32: lane L holds B[k=(L>>4)*8+t][n=L&15] ->
// W[g*H + jg*16 + (L&15)][kb*32 + (L>>4)*8 + t].
// Chunk c = (((g*64+jg)*32 + kb)*4 + q)*16 + r ; 16B per chunk-lane.
// ---------------------------------------------------------------------------
__global__ void gru_setup(const float* __restrict__ WhhE,
                          const float* __restrict__ WhhD,
                          const float* __restrict__ WihE,
                          char* __restrict__ ws) {
  int t = blockIdx.x * 256 + threadIdx.x;
  if (t < 512) ((unsigned int*)(ws + BARS))[t] = 0u;
  const int NW = 3 * 64 * 32 * 4 * 16;
  if (t < 2 * NW) {
    const float* W = (t < NW) ? WhhE : WhhD;
    size_t dst = (t < NW) ? WF_E : WF_D;
    int c = (t < NW) ? t : t - NW;
    int r = c & 15, q = (c >> 4) & 3, kb = (c >> 6) & 31, gj = c >> 11;
    int row = (gj >> 6) * H_ + (gj & 63) * 16 + r;
    const float* src = W + (size_t)row * H_ + kb * 32 + q * 8;
    half8 v;
#pragma unroll
    for (int i = 0; i < 8; ++i) v[i] = (_Float16)src[i];
    *(half8*)(ws + dst + (size_t)c * 16) = v;
  } else if (t < 2 * NW + 3 * 64 * 2 * 4 * 16) {
    int c = t - 2 * NW;
    int r = c & 15, q = (c >> 4) & 3, kc = (c >> 6) & 1, gj = c >> 7;
    int row = (gj >> 6) * H_ + (gj & 63) * 16 + r;
    const float* src = WihE + (size_t)row * F_ + kc * 32 + q * 8;
    half8 v;
#pragma unroll
    for (int i = 0; i < 8; ++i) v[i] = (_Float16)src[i];
    *(half8*)(ws + WF_I + (size_t)c * 16) = v;
  }
}

// Group barrier: 8 blocks (same rg), own cacheline, relaxed LLC atomics.
__device__ __forceinline__ void gbar(unsigned int* cnt, unsigned int target) {
  __syncthreads();
  if (threadIdx.x == 0) {
    __hip_atomic_fetch_add(cnt, 1u, __ATOMIC_RELAXED,
                           __HIP_MEMORY_SCOPE_AGENT);
    while (__hip_atomic_load(cnt, __ATOMIC_RELAXED,
                             __HIP_MEMORY_SCOPE_AGENT) < target)
      __builtin_amdgcn_s_sleep(1);
  }
  __syncthreads();
}

// ---------------------------------------------------------------------------
// Main persistent kernel: 128 blocks x 1024 thr (16 waves, 1 block/CU).
// Block (rg = bx&15, cb2 = bx>>4): rows [rg*16,+16), h-cols [cb2*128,+128).
// Wave w: jp = w&7 (jg = cb2*8+jp), kh = w>>3 (K-half); bW = 48 chunks.
// Model (rounds 4-8): the binding resource is the coherent-fabric path
// (~3.5 TB/s measured). Staging bytes/step = blocks/group x 64KB x 16
// groups; going 16 -> 8 blocks/group halves it to 8 MB/step. Register
// experiments (rounds 6-8) proved bW residency is NOT the bottleneck (W
// re-reads are L2 hits), but we still AGPR-pin bW since at 4 waves/SIMD
// the 512-reg budget comfortably fits 192 AGPR + arch.
// ---------------------------------------------------------------------------
__global__ __attribute__((amdgpu_flat_work_group_size(1024, 1024))) void
gru_main(
    const float* __restrict__ x,
    const float* __restrict__ bih_e, const float* __restrict__ bhh_e,
    const float* __restrict__ Wih_d,
    const float* __restrict__ bih_d, const float* __restrict__ bhh_d,
    const float* __restrict__ fcW, const float* __restrict__ fcb,
    float* __restrict__ out, char* __restrict__ ws) {

  __shared__ __align__(128) char atile[65536];  // [plane 2][kb 32][L 64][16B]
  __shared__ float red[8 * 64 * 17];            // kh1 partials [jp][L][17]
  __shared__ __align__(16) char otile[8192];    // h' image [plane 2][4KB]
  __shared__ float inp_lds[16];

  const int tid = threadIdx.x;
  const int L = tid & 63;
  const int w = tid >> 6;
  const int jp = w & 7;
  const int kh = w >> 3;
  const int bx = blockIdx.x;
  const int rg = bx & 15;
  const int cb2 = bx >> 4;
  const int r = L & 15;
  const int q = L >> 4;
  const int jg = cb2 * 8 + jp;
  const int jc = jg * 16 + r;

  unsigned int* bar = (unsigned int*)(ws + BARS) + (size_t)rg * 32;
  unsigned int bt = 0;

  // stream-out mapping: thread -> (plane, 8B unit) of the block's own 4KB
  const int so_plane = tid >> 9;
  const int so_i = tid & 511;
  const size_t slab = (size_t)rg * 32768;

  // zero own h'-region of parity 0 (8KB/block, 128 blocks = full 1MB)
  sta8(ws + HP + (size_t)so_plane * HPLANE + slab + (size_t)cb2 * 4096 +
           (size_t)so_i * 8,
       0ull);

  float hold[4] = {0.f, 0.f, 0.f, 0.f};
  const float fcb_s = *fcb;
  const float fcw_l = fcW[jc];

  bt += 8;
  gbar(bar, bt);

  for (int phase = 0; phase < 2; ++phase) {
    // AGPR-resident W_hh B-frags for (jg, kh): [gate][kk].
    half8 bW[48];
    {
      const char* wf = ws + (phase ? WF_D : WF_E);
#pragma unroll
      for (int g = 0; g < 3; ++g)
#pragma unroll
        for (int kk = 0; kk < 16; ++kk)
          bW[g * 16 + kk] = *(const half8*)(
              wf + (size_t)((g * 64 + jg) * 32 + kh * 16 + kk) * 1024 +
              (size_t)L * 16);
#pragma unroll
      for (int i = 0; i < 48; ++i) asm volatile("" : "+a"(bW[i]));
    }
    const float* bih = phase ? bih_d : bih_e;
    const float* bhh = phase ? bhh_d : bhh_e;
    const float b_r  = bih[jc]          + bhh[jc];
    const float b_z  = bih[H_ + jc]     + bhh[H_ + jc];
    const float b_in = bih[2 * H_ + jc];
    const float b_hn = bhh[2 * H_ + jc];
    float wd_r = 0.f, wd_z = 0.f, wd_n = 0.f;
    if (phase) {
      wd_r = Wih_d[jc]; wd_z = Wih_d[H_ + jc]; wd_n = Wih_d[2 * H_ + jc];
    }

    const int nsteps = phase ? TL_ : T_;
    for (int d = 0; d < nsteps; ++d) {
      const int s = phase ? T_ + d : d;

      // ---- stage A slab (hi+lo, 64KB) via async global->LDS DMA,
      //      LLC-coherent (aux 17 = sc0|sc1). Wave w stages segments
      //      w*4..w*4+3; lane L's 16B lands at seg base + L*16. ----
      {
        const char* srcbase = ws + HP + (size_t)(s & 1) * (2 * HPLANE) + slab;
#pragma unroll
        for (int c = 0; c < 4; ++c) {
          const int seg = w * 4 + c;       // 0..63
          const int plane = seg >> 5;      // hi / lo
          const int kb = seg & 31;
          const char* src = srcbase + (size_t)plane * HPLANE +
                            (size_t)kb * 1024 + (size_t)L * 16;
          __builtin_amdgcn_global_load_lds(
              (const __attribute__((address_space(1))) void*)src,
              (__attribute__((address_space(3))) void*)(atile + seg * 1024),
              16, 0, 17);
        }
      }

      // ---- decoder scalar input (overlaps the staging DMA) ----
      if (phase && tid < 16) {
        float sum = 0.f;
        if (d > 0) {
          const float* pb =
              (const float*)(ws + PB) + (size_t)((d + 1) & 1) * 64 * 256;
          int row = rg * 16 + tid;
          float a = fcb_s;
          for (int jj = 0; jj < 64; ++jj) a += lda4f(&pb[jj * 256 + row]);
          sum = a;
          if (cb2 == 0) out[(size_t)row * TL_ + (d - 1)] = a;
        }
        inp_lds[tid] = sum;
      }
      __syncthreads();  // drains vmcnt -> DMA complete

      floatx4 a0 = {0.f, 0.f, 0.f, 0.f}, a1 = {0.f, 0.f, 0.f, 0.f};
      floatx4 a2 = {0.f, 0.f, 0.f, 0.f}, aI = {0.f, 0.f, 0.f, 0.f};

      // ---- h-GEMM, this wave's K-half, hi+lo planes (stride-1 ds_read) ----
#pragma unroll
      for (int kk = 0; kk < 16; ++kk) {
        const int kb = kh * 16 + kk;
        half8 ahi = *(const half8*)(atile + kb * 1024 + L * 16);
        half8 alo = *(const half8*)(atile + 32768 + kb * 1024 + L * 16);
        a0 = MFMA(ahi, bW[kk], a0);
        a0 = MFMA(alo, bW[kk], a0);
        a1 = MFMA(ahi, bW[16 + kk], a1);
        a1 = MFMA(alo, bW[16 + kk], a1);
        a2 = MFMA(ahi, bW[32 + kk], a2);
        a2 = MFMA(alo, bW[32 + kk], a2);
      }

      // ---- kh1: encoder x-projection + dump partials ----
      if (kh == 1) {
        if (!phase) {
          const float* xp =
              x + ((size_t)(rg * 16 + r) * T_ + s) * F_ + q * 8;
          const char* wfi = ws + WF_I + (size_t)L * 16;  // L1/L2-hot reloads
#pragma unroll
          for (int kc = 0; kc < 2; ++kc) {
            floatx4 x0 = *(const floatx4*)(xp + kc * 32);
            floatx4 x1 = *(const floatx4*)(xp + kc * 32 + 4);
            half8 xa;
#pragma unroll
            for (int i = 0; i < 4; ++i) {
              xa[i] = (_Float16)x0[i];
              xa[4 + i] = (_Float16)x1[i];
            }
            a0 = MFMA(xa, *(const half8*)(wfi +
                     (size_t)((0 * 64 + jg) * 2 + kc) * 1024), a0);
            a1 = MFMA(xa, *(const half8*)(wfi +
                     (size_t)((1 * 64 + jg) * 2 + kc) * 1024), a1);
            aI = MFMA(xa, *(const half8*)(wfi +
                     (size_t)((2 * 64 + jg) * 2 + kc) * 1024), aI);
          }
        }
        float* rd = &red[(jp * 64 + L) * 17];
#pragma unroll
        for (int i = 0; i < 4; ++i) {
          rd[i] = a0[i];
          rd[4 + i] = a1[i];
          rd[8 + i] = a2[i];
        }
        if (!phase) {
#pragma unroll
          for (int i = 0; i < 4; ++i) rd[12 + i] = aI[i];
        }
      }
      __syncthreads();

      // ---- kh0: reduce halves, gate epilogue, h' -> otile ----
      if (kh == 0) {
        const float* rd = &red[(jp * 64 + L) * 17];
        const size_t tbase = (size_t)(jp >> 1) * 1024 +
                             (size_t)((jp & 1) * 2 + (r >> 3)) * 256 +
                             (size_t)(r & 7) * 2;
        float pv[4];
#pragma unroll
        for (int i = 0; i < 4; ++i) {
          float rpre = a0[i] + rd[i] + b_r;
          float zpre = a1[i] + rd[4 + i] + b_z;
          float hn   = a2[i] + rd[8 + i] + b_hn;
          float inn  = b_in + (phase ? 0.f : rd[12 + i]);
          if (phase) {
            float inp = inp_lds[q * 4 + i];
            rpre += inp * wd_r;
            zpre += inp * wd_z;
            inn  += inp * wd_n;
          }
          float rg_ = 1.f / (1.f + __expf(-rpre));
          float zg = 1.f / (1.f + __expf(-zpre));
          float t2 = __expf(-2.f * (inn + rg_ * hn));
          float ng = 2.f / (1.f + t2) - 1.f;  // tanh, safe at +-inf
          float hnew = (1.f - zg) * ng + zg * hold[i];
          hold[i] = hnew;
          _Float16 hhi = (_Float16)hnew;
          float lo = hnew - (float)hhi;
          _Float16 hlo = (_Float16)lo;
          size_t to = tbase + (size_t)(q * 4 + i) * 16;
          *(_Float16*)(otile + to) = hhi;
          *(_Float16*)(otile + 4096 + to) = hlo;
          pv[i] = hnew * fcw_l;
        }
        if (phase) {
#pragma unroll
          for (int i = 0; i < 4; ++i) {
            float v = pv[i];
            v += __shfl_xor(v, 1);
            v += __shfl_xor(v, 2);
            v += __shfl_xor(v, 4);
            v += __shfl_xor(v, 8);
            if (r == 0) {
              float* pb = (float*)(ws + PB) + (size_t)(d & 1) * 64 * 256;
              __hip_atomic_store(&pb[jg * 256 + (rg * 16 + q * 4 + i)], v,
                                 __ATOMIC_RELAXED, __HIP_MEMORY_SCOPE_AGENT);
            }
          }
        }
      }
      __syncthreads();

      // ---- stream h' (8KB) out: coalesced 8B LLC stores ----
      {
        ull v = *(const ull*)(otile + (size_t)so_plane * 4096 +
                              (size_t)so_i * 8);
        sta8(ws + HP + (size_t)((s + 1) & 1) * (2 * HPLANE) +
                 (size_t)so_plane * HPLANE + slab + (size_t)cb2 * 4096 +
                 (size_t)so_i * 8,
             v);
      }

      bt += 8;
      gbar(bar, bt);
    }
  }

  // ---- final output column t = TL-1 ----
  if (cb2 == 0 && tid < 16) {
    const float* pb =
        (const float*)(ws + PB) + (size_t)((TL_ - 1) & 1) * 64 * 256;
    int row = rg * 16 + tid;
    float a = fcb_s;
    for (int jj = 0; jj < 64; ++jj) a += lda4f(&pb[jj * 256 + row]);
    out[(size_t)row * TL_ + (TL_ - 1)] = a;
  }
}

// ---------------------------------------------------------------------------
extern "C" void kernel_launch(void* const* d_in, const int* in_sizes, int n_in,
                              void* d_out, int out_size, void* d_ws,
                              size_t ws_size, hipStream_t stream) {
  const float* x     = (const float*)d_in[0];
  const float* WihE  = (const float*)d_in[1];
  const float* WhhE  = (const float*)d_in[2];
  const float* bihE  = (const float*)d_in[3];
  const float* bhhE  = (const float*)d_in[4];
  const float* WihD  = (const float*)d_in[5];
  const float* WhhD  = (const float*)d_in[6];
  const float* bihD  = (const float*)d_in[7];
  const float* bhhD  = (const float*)d_in[8];
  const float* fcW   = (const float*)d_in[9];
  const float* fcb   = (const float*)d_in[10];
  float* outp = (float*)d_out;
  char* ws = (char*)d_ws;

  gru_setup<<<3168, 256, 0, stream>>>(WhhE, WhhD, WihE, ws);

  gru_main<<<dim3(128), dim3(1024), 0, stream>>>(
      x, bihE, bhhE, WihD, bihD, bhhD, fcW, fcb, outp, ws);
}

// Round 10
// 9198.266 us; speedup vs baseline: 1.4742x; 1.4742x over previous
//
#include <hip/hip_runtime.h>

#define B_  256
#define T_  512
#define F_  64
#define H_  1024
#define TL_ 64

typedef _Float16 half8 __attribute__((ext_vector_type(8)));
typedef float   floatx4 __attribute__((ext_vector_type(4)));
typedef float   floatx2 __attribute__((ext_vector_type(2)));
typedef unsigned long long ull;

#define MFMA(a, b, c) __builtin_amdgcn_mfma_f32_16x16x32_f16(a, b, c, 0, 0, 0)

// ws layout (bytes)
#define WF_E   0UL          // W_hh enc fragments: 3*64*32 chunks * 1024B
#define WF_D   6291456UL    // W_hh dec fragments
#define WF_I   12582912UL   // W_ih enc fragments: 3*64*2 chunks * 1024B
#define HP     12976128UL   // h planes: [2 parity][hi fp16 512KB | lo fp8 256KB]
#define PSTR   786432UL     // parity stride (768KB)
#define LOOFF  524288UL     // lo-plane offset within a parity
#define PB     15073280UL   // fc partials: [2][64 jg][256 rows] f32
#define BARS   15204352UL   // 16 group counters, 128B apart
// hi plane (fragment-major fp16): [rg 16][kb 32][lane 64][16B]; slab 32KB/rg;
// block (rg,cb) owns the contiguous 2KB at rg*32768 + cb*2048.
// lo plane (fp8 e4m3, value = lo * 2^16): [rg 16][kb 32][lane 64][8B];
// slab 16KB/rg; block owns 1KB at rg*16384 + cb*1024.

// LLC-coherent scalar atomics (sc0 sc1: bypass L1/L2, coherent at IF).
__device__ __forceinline__ void sta8(void* p, ull v) {
  __hip_atomic_store((ull*)p, v, __ATOMIC_RELAXED, __HIP_MEMORY_SCOPE_AGENT);
}
__device__ __forceinline__ float lda4f(const float* p) {
  return __hip_atomic_load(p, __ATOMIC_RELAXED, __HIP_MEMORY_SCOPE_AGENT);
}

// decode 8 packed fp8 e4m3 (scaled 2^16) -> half8 of the residual
__device__ __forceinline__ half8 decode_lo(ull v) {
  int l = (int)(v & 0xffffffffull), h = (int)(v >> 32);
  floatx2 f01 = __builtin_amdgcn_cvt_pk_f32_fp8(l, false);
  floatx2 f23 = __builtin_amdgcn_cvt_pk_f32_fp8(l, true);
  floatx2 f45 = __builtin_amdgcn_cvt_pk_f32_fp8(h, false);
  floatx2 f67 = __builtin_amdgcn_cvt_pk_f32_fp8(h, true);
  const float S = 1.52587890625e-05f;  // 2^-16
  half8 r;
  r[0] = (_Float16)(f01[0] * S); r[1] = (_Float16)(f01[1] * S);
  r[2] = (_Float16)(f23[0] * S); r[3] = (_Float16)(f23[1] * S);
  r[4] = (_Float16)(f45[0] * S); r[5] = (_Float16)(f45[1] * S);
  r[6] = (_Float16)(f67[0] * S); r[7] = (_Float16)(f67[1] * S);
  return r;
}

// ---------------------------------------------------------------------------
// Setup: W_hh (enc,dec) and W_ih (enc) fp32 -> fp16 MFMA-B fragment layout.
// B-frag 16x16x32: lane L holds B[k=(L>>4)*8+t][n=L&15] ->
// W[g*H + jg*16 + (L&15)][kb*32 + (L>>4)*8 + t].
// Chunk c = (((g*64+jg)*32 + kb)*4 + q)*16 + r ; 16B per chunk-lane.
// ---------------------------------------------------------------------------
__global__ void gru_setup(const float* __restrict__ WhhE,
                          const float* __restrict__ WhhD,
                          const float* __restrict__ WihE,
                          char* __restrict__ ws) {
  int t = blockIdx.x * 256 + threadIdx.x;
  if (t < 512) ((unsigned int*)(ws + BARS))[t] = 0u;
  const int NW = 3 * 64 * 32 * 4 * 16;
  if (t < 2 * NW) {
    const float* W = (t < NW) ? WhhE : WhhD;
    size_t dst = (t < NW) ? WF_E : WF_D;
    int c = (t < NW) ? t : t - NW;
    int r = c & 15, q = (c >> 4) & 3, kb = (c >> 6) & 31, gj = c >> 11;
    int row = (gj >> 6) * H_ + (gj & 63) * 16 + r;
    const float* src = W + (size_t)row * H_ + kb * 32 + q * 8;
    half8 v;
#pragma unroll
    for (int i = 0; i < 8; ++i) v[i] = (_Float16)src[i];
    *(half8*)(ws + dst + (size_t)c * 16) = v;
  } else if (t < 2 * NW + 3 * 64 * 2 * 4 * 16) {
    int c = t - 2 * NW;
    int r = c & 15, q = (c >> 4) & 3, kc = (c >> 6) & 1, gj = c >> 7;
    int row = (gj >> 6) * H_ + (gj & 63) * 16 + r;
    const float* src = WihE + (size_t)row * F_ + kc * 32 + q * 8;
    half8 v;
#pragma unroll
    for (int i = 0; i < 8; ++i) v[i] = (_Float16)src[i];
    *(half8*)(ws + WF_I + (size_t)c * 16) = v;
  }
}

// Group barrier: 16 blocks (same rg), own cacheline, relaxed LLC atomics.
__device__ __forceinline__ void gbar(unsigned int* cnt, unsigned int target) {
  __syncthreads();
  if (threadIdx.x == 0) {
    __hip_atomic_fetch_add(cnt, 1u, __ATOMIC_RELAXED,
                           __HIP_MEMORY_SCOPE_AGENT);
    while (__hip_atomic_load(cnt, __ATOMIC_RELAXED,
                             __HIP_MEMORY_SCOPE_AGENT) < target)
      __builtin_amdgcn_s_sleep(1);
  }
  __syncthreads();
}

// ---------------------------------------------------------------------------
// Main persistent kernel: 256 blocks x 512 thr (8 waves) — the round-6
// champion shape (512thr/2waves-per-SIMD; round 9 proved 1024thr kills the
// register budget: 128/wave -> bW spills to HBM, 13.6ms). Block (rg=bx&15,
// cb=bx>>4): rows [rg*16,+16), h-cols [cb*64,+64). Wave w: jp=w&3
// (jg=cb*4+jp), kh=w>>2. Staged A bytes cut 4B -> 3B/element: hi fp16 +
// lo fp8-e4m3 (residual*2^16; h storage err 2^-16/step, accum ~3e-4, safe
// vs 1.6e-3). Coherent-fabric staging: 16 -> 12 MB/step.
// ---------------------------------------------------------------------------
__global__ __launch_bounds__(512, 2) void gru_main(
    const float* __restrict__ x,
    const float* __restrict__ bih_e, const float* __restrict__ bhh_e,
    const float* __restrict__ Wih_d,
    const float* __restrict__ bih_d, const float* __restrict__ bhh_d,
    const float* __restrict__ fcW, const float* __restrict__ fcb,
    float* __restrict__ out, char* __restrict__ ws) {

  __shared__ __align__(128) char atile[49152];  // hi 32KB | lo-fp8 16KB
  __shared__ float red[4 * 64 * 17];            // kh1 partials [jp][L][17]
  __shared__ __align__(16) char otile[3072];    // h' image: hi 2KB | lo 1KB
  __shared__ float inp_lds[16];

  const int tid = threadIdx.x;
  const int L = tid & 63;
  const int w = tid >> 6;
  const int jp = w & 3;
  const int kh = w >> 2;
  const int bx = blockIdx.x;
  const int rg = bx & 15;
  const int cb = bx >> 4;
  const int r = L & 15;
  const int q = L >> 4;
  const int jg = cb * 4 + jp;
  const int jc = jg * 16 + r;

  unsigned int* bar = (unsigned int*)(ws + BARS) + (size_t)rg * 32;
  unsigned int bt = 0;

  const size_t slab = (size_t)rg * 32768;      // hi slab
  const size_t slab8 = (size_t)rg * 16384;     // lo slab

  // zero own h'-region of parity 0: hi 2KB (tid<256), lo 1KB (tid 256..383)
  if (tid < 256) {
    sta8(ws + HP + slab + (size_t)cb * 2048 + (size_t)tid * 8, 0ull);
  } else if (tid < 384) {
    sta8(ws + HP + LOOFF + slab8 + (size_t)cb * 1024 + (size_t)(tid - 256) * 8,
         0ull);
  }

  float hold[4] = {0.f, 0.f, 0.f, 0.f};
  const float fcb_s = *fcb;
  const float fcw_l = fcW[jc];

  bt += 16;
  gbar(bar, bt);

  for (int phase = 0; phase < 2; ++phase) {
    // register-resident W_hh B-frags for (jg, kh): [gate][kk].
    half8 bW[48];
    {
      const char* wf = ws + (phase ? WF_D : WF_E);
#pragma unroll
      for (int g = 0; g < 3; ++g)
#pragma unroll
        for (int kk = 0; kk < 16; ++kk)
          bW[g * 16 + kk] = *(const half8*)(
              wf + (size_t)((g * 64 + jg) * 32 + kh * 16 + kk) * 1024 +
              (size_t)L * 16);
#pragma unroll
      for (int i = 0; i < 48; ++i) asm volatile("" : "+v"(bW[i]));
    }
    const float* bih = phase ? bih_d : bih_e;
    const float* bhh = phase ? bhh_d : bhh_e;
    const float b_r  = bih[jc]          + bhh[jc];
    const float b_z  = bih[H_ + jc]     + bhh[H_ + jc];
    const float b_in = bih[2 * H_ + jc];
    const float b_hn = bhh[2 * H_ + jc];
    float wd_r = 0.f, wd_z = 0.f, wd_n = 0.f;
    if (phase) {
      wd_r = Wih_d[jc]; wd_z = Wih_d[H_ + jc]; wd_n = Wih_d[2 * H_ + jc];
    }

    const int nsteps = phase ? TL_ : T_;
    for (int d = 0; d < nsteps; ++d) {
      const int s = phase ? T_ + d : d;

      // ---- stage A slab (hi 32KB + lo-fp8 16KB) via async global->LDS DMA,
      //      LLC-coherent (aux 17 = sc0|sc1). 48 segs of 1KB; wave w takes
      //      segs w*6..w*6+5. ----
      {
        const char* pbase = ws + HP + (size_t)(s & 1) * PSTR;
#pragma unroll
        for (int c = 0; c < 6; ++c) {
          const int seg = w * 6 + c;  // 0..47
          const char* src;
          char* dstl;
          if (seg < 32) {  // hi plane
            src = pbase + slab + (size_t)seg * 1024 + (size_t)L * 16;
            dstl = atile + seg * 1024;
          } else {         // lo plane (fp8)
            const int sl = seg - 32;
            src = pbase + LOOFF + slab8 + (size_t)sl * 1024 + (size_t)L * 16;
            dstl = atile + 32768 + sl * 1024;
          }
          __builtin_amdgcn_global_load_lds(
              (const __attribute__((address_space(1))) void*)src,
              (__attribute__((address_space(3))) void*)dstl, 16, 0, 17);
        }
      }

      // ---- decoder scalar input (overlaps the staging DMA) ----
      if (phase && tid < 16) {
        float sum = 0.f;
        if (d > 0) {
          const float* pb =
              (const float*)(ws + PB) + (size_t)((d + 1) & 1) * 64 * 256;
          int row = rg * 16 + tid;
          float a = fcb_s;
          for (int jj = 0; jj < 64; ++jj) a += lda4f(&pb[jj * 256 + row]);
          sum = a;
          if (cb == 0) out[(size_t)row * TL_ + (d - 1)] = a;
        }
        inp_lds[tid] = sum;
      }
      __syncthreads();  // drains vmcnt -> DMA complete

      floatx4 a0 = {0.f, 0.f, 0.f, 0.f}, a1 = {0.f, 0.f, 0.f, 0.f};
      floatx4 a2 = {0.f, 0.f, 0.f, 0.f}, aI = {0.f, 0.f, 0.f, 0.f};

      // ---- h-GEMM, this wave's K-half; hi fp16 + decoded fp8 residual ----
#pragma unroll
      for (int kk = 0; kk < 16; ++kk) {
        const int kb = kh * 16 + kk;
        half8 ahi = *(const half8*)(atile + kb * 1024 + L * 16);
        ull lov = *(const ull*)(atile + 32768 + kb * 512 + L * 8);
        half8 alo = decode_lo(lov);
        a0 = MFMA(ahi, bW[kk], a0);
        a0 = MFMA(alo, bW[kk], a0);
        a1 = MFMA(ahi, bW[16 + kk], a1);
        a1 = MFMA(alo, bW[16 + kk], a1);
        a2 = MFMA(ahi, bW[32 + kk], a2);
        a2 = MFMA(alo, bW[32 + kk], a2);
      }

      // ---- kh1: encoder x-projection + dump partials ----
      if (kh == 1) {
        if (!phase) {
          const float* xp =
              x + ((size_t)(rg * 16 + r) * T_ + s) * F_ + q * 8;
          const char* wfi = ws + WF_I + (size_t)L * 16;  // L1/L2-hot reloads
#pragma unroll
          for (int kc = 0; kc < 2; ++kc) {
            floatx4 x0 = *(const floatx4*)(xp + kc * 32);
            floatx4 x1 = *(const floatx4*)(xp + kc * 32 + 4);
            half8 xa;
#pragma unroll
            for (int i = 0; i < 4; ++i) {
              xa[i] = (_Float16)x0[i];
              xa[4 + i] = (_Float16)x1[i];
            }
            a0 = MFMA(xa, *(const half8*)(wfi +
                     (size_t)((0 * 64 + jg) * 2 + kc) * 1024), a0);
            a1 = MFMA(xa, *(const half8*)(wfi +
                     (size_t)((1 * 64 + jg) * 2 + kc) * 1024), a1);
            aI = MFMA(xa, *(const half8*)(wfi +
                     (size_t)((2 * 64 + jg) * 2 + kc) * 1024), aI);
          }
        }
        float* rd = &red[(jp * 64 + L) * 17];
#pragma unroll
        for (int i = 0; i < 4; ++i) {
          rd[i] = a0[i];
          rd[4 + i] = a1[i];
          rd[8 + i] = a2[i];
        }
        if (!phase) {
#pragma unroll
          for (int i = 0; i < 4; ++i) rd[12 + i] = aI[i];
        }
      }
      __syncthreads();

      // ---- kh0: reduce halves, gate epilogue, h' -> otile (hi + fp8 lo) ----
      if (kh == 0) {
        const float* rd = &red[(jp * 64 + L) * 17];
        const size_t tbase = (size_t)(jp >> 1) * 1024 +
                             (size_t)((jp & 1) * 2 + (r >> 3)) * 256 +
                             (size_t)(r & 7) * 2;
        const size_t lob = 2048 + (size_t)(jp >> 1) * 512 +
                           (size_t)((jp & 1) * 2 + (r >> 3)) * 128 +
                           (size_t)(r & 7);
        float pv[4], los[4];
#pragma unroll
        for (int i = 0; i < 4; ++i) {
          float rpre = a0[i] + rd[i] + b_r;
          float zpre = a1[i] + rd[4 + i] + b_z;
          float hn   = a2[i] + rd[8 + i] + b_hn;
          float inn  = b_in + (phase ? 0.f : rd[12 + i]);
          if (phase) {
            float inp = inp_lds[q * 4 + i];
            rpre += inp * wd_r;
            zpre += inp * wd_z;
            inn  += inp * wd_n;
          }
          float rg_ = 1.f / (1.f + __expf(-rpre));
          float zg = 1.f / (1.f + __expf(-zpre));
          float t2 = __expf(-2.f * (inn + rg_ * hn));
          float ng = 2.f / (1.f + t2) - 1.f;  // tanh, safe at +-inf
          float hnew = (1.f - zg) * ng + zg * hold[i];
          hold[i] = hnew;
          _Float16 hhi = (_Float16)hnew;
          *(_Float16*)(otile + tbase + (size_t)(q * 4 + i) * 16) = hhi;
          los[i] = (hnew - (float)hhi) * 65536.0f;  // residual * 2^16
          pv[i] = hnew * fcw_l;
        }
        {
          int p01 = __builtin_amdgcn_cvt_pk_fp8_f32(los[0], los[1], 0, false);
          int p23 = __builtin_amdgcn_cvt_pk_fp8_f32(los[2], los[3], 0, false);
          otile[lob + (size_t)(q * 4 + 0) * 8] = (char)(p01 & 0xff);
          otile[lob + (size_t)(q * 4 + 1) * 8] = (char)((p01 >> 8) & 0xff);
          otile[lob + (size_t)(q * 4 + 2) * 8] = (char)(p23 & 0xff);
          otile[lob + (size_t)(q * 4 + 3) * 8] = (char)((p23 >> 8) & 0xff);
        }
        if (phase) {
#pragma unroll
          for (int i = 0; i < 4; ++i) {
            float v = pv[i];
            v += __shfl_xor(v, 1);
            v += __shfl_xor(v, 2);
            v += __shfl_xor(v, 4);
            v += __shfl_xor(v, 8);
            if (r == 0) {
              float* pb = (float*)(ws + PB) + (size_t)(d & 1) * 64 * 256;
              __hip_atomic_store(&pb[jg * 256 + (rg * 16 + q * 4 + i)], v,
                                 __ATOMIC_RELAXED, __HIP_MEMORY_SCOPE_AGENT);
            }
          }
        }
      }
      __syncthreads();

      // ---- stream h' out: hi 2KB (tid<256) + lo 1KB (tid 256..383) ----
      {
        char* pdst = ws + HP + (size_t)((s + 1) & 1) * PSTR;
        if (tid < 256) {
          ull v = *(const ull*)(otile + (size_t)tid * 8);
          sta8(pdst + slab + (size_t)cb * 2048 + (size_t)tid * 8, v);
        } else if (tid < 384) {
          const int i8 = tid - 256;
          ull v = *(const ull*)(otile + 2048 + (size_t)i8 * 8);
          sta8(pdst + LOOFF + slab8 + (size_t)cb * 1024 + (size_t)i8 * 8, v);
        }
      }

      bt += 16;
      gbar(bar, bt);
    }
  }

  // ---- final output column t = TL-1 ----
  if (cb == 0 && tid < 16) {
    const float* pb =
        (const float*)(ws + PB) + (size_t)((TL_ - 1) & 1) * 64 * 256;
    int row = rg * 16 + tid;
    float a = fcb_s;
    for (int jj = 0; jj < 64; ++jj) a += lda4f(&pb[jj * 256 + row]);
    out[(size_t)row * TL_ + (TL_ - 1)] = a;
  }
}

// ---------------------------------------------------------------------------
extern "C" void kernel_launch(void* const* d_in, const int* in_sizes, int n_in,
                              void* d_out, int out_size, void* d_ws,
                              size_t ws_size, hipStream_t stream) {
  const float* x     = (const float*)d_in[0];
  const float* WihE  = (const float*)d_in[1];
  const float* WhhE  = (const float*)d_in[2];
  const float* bihE  = (const float*)d_in[3];
  const float* bhhE  = (const float*)d_in[4];
  const float* WihD  = (const float*)d_in[5];
  const float* WhhD  = (const float*)d_in[6];
  const float* bihD  = (const float*)d_in[7];
  const float* bhhD  = (const float*)d_in[8];
  const float* fcW   = (const float*)d_in[9];
  const float* fcb   = (const float*)d_in[10];
  float* outp = (float*)d_out;
  char* ws = (char*)d_ws;

  gru_setup<<<3168, 256, 0, stream>>>(WhhE, WhhD, WihE, ws);

  gru_main<<<dim3(256), dim3(512), 0, stream>>>(
      x, bihE, bhhE, WihD, bihD, bhhD, fcW, fcb, outp, ws);
}

// Round 11
// 2716.402 us; speedup vs baseline: 4.9919x; 3.3862x over previous
//
#include <hip/hip_runtime.h>

#define B_  256
#define T_  512
#define F_  64
#define H_  1024
#define TL_ 64

typedef _Float16 half8 __attribute__((ext_vector_type(8)));
typedef float   floatx4 __attribute__((ext_vector_type(4)));
typedef unsigned long long ull;

#define MFMA(a, b, c) __builtin_amdgcn_mfma_f32_16x16x32_f16(a, b, c, 0, 0, 0)

// ws layout (bytes)
#define WF_E   0UL          // W_hh enc fragments: 3*64*32 chunks * 1024B
#define WF_D   6291456UL    // W_hh dec fragments
#define WF_I   12582912UL   // W_ih enc fragments: 3*64*2 chunks * 1024B
#define HP     12976128UL   // h planes: [2 parity][hi fp16 512KB]
#define PSTR   524288UL     // parity stride
#define PB     15073280UL   // fc partials: [2][64 jg][256 rows] f32
#define BARS   15204352UL   // 16 group counters, 128B apart
// h plane (fragment-major fp16): [rg 16][kb 32][lane 64][16B]; slab 32KB/rg;
// block (rg,cb) owns the contiguous 2KB at rg*32768 + cb*2048.
// NOTE (r10 postmortem): h is stored fp16-only. Each element's own
// recurrence (z*h_old) stays in fp32 registers (hold[]), so storage error
// enters only via the contractive GEMM path: expected absmax ~3-6e-4.

// LLC-coherent scalar atomics (sc0 sc1: bypass L1/L2, coherent at IF).
__device__ __forceinline__ void sta8(void* p, ull v) {
  __hip_atomic_store((ull*)p, v, __ATOMIC_RELAXED, __HIP_MEMORY_SCOPE_AGENT);
}
__device__ __forceinline__ float lda4f(const float* p) {
  return __hip_atomic_load(p, __ATOMIC_RELAXED, __HIP_MEMORY_SCOPE_AGENT);
}

// ---------------------------------------------------------------------------
// Setup: W_hh (enc,dec) and W_ih (enc) fp32 -> fp16 MFMA-B fragment layout.
// B-frag 16x16x32: lane L holds B[k=(L>>4)*8+t][n=L&15] ->
// W[g*H + jg*16 + (L&15)][kb*32 + (L>>4)*8 + t].
// Chunk c = (((g*64+jg)*32 + kb)*4 + q)*16 + r ; 16B per chunk-lane.
// ---------------------------------------------------------------------------
__global__ void gru_setup(const float* __restrict__ WhhE,
                          const float* __restrict__ WhhD,
                          const float* __restrict__ WihE,
                          char* __restrict__ ws) {
  int t = blockIdx.x * 256 + threadIdx.x;
  if (t < 512) ((unsigned int*)(ws + BARS))[t] = 0u;
  const int NW = 3 * 64 * 32 * 4 * 16;
  if (t < 2 * NW) {
    const float* W = (t < NW) ? WhhE : WhhD;
    size_t dst = (t < NW) ? WF_E : WF_D;
    int c = (t < NW) ? t : t - NW;
    int r = c & 15, q = (c >> 4) & 3, kb = (c >> 6) & 31, gj = c >> 11;
    int row = (gj >> 6) * H_ + (gj & 63) * 16 + r;
    const float* src = W + (size_t)row * H_ + kb * 32 + q * 8;
    half8 v;
#pragma unroll
    for (int i = 0; i < 8; ++i) v[i] = (_Float16)src[i];
    *(half8*)(ws + dst + (size_t)c * 16) = v;
  } else if (t < 2 * NW + 3 * 64 * 2 * 4 * 16) {
    int c = t - 2 * NW;
    int r = c & 15, q = (c >> 4) & 3, kc = (c >> 6) & 1, gj = c >> 7;
    int row = (gj >> 6) * H_ + (gj & 63) * 16 + r;
    const float* src = WihE + (size_t)row * F_ + kc * 32 + q * 8;
    half8 v;
#pragma unroll
    for (int i = 0; i < 8; ++i) v[i] = (_Float16)src[i];
    *(half8*)(ws + WF_I + (size_t)c * 16) = v;
  }
}

// Group barrier: 16 blocks (same rg), own cacheline, relaxed LLC atomics.
__device__ __forceinline__ void gbar(unsigned int* cnt, unsigned int target) {
  __syncthreads();
  if (threadIdx.x == 0) {
    __hip_atomic_fetch_add(cnt, 1u, __ATOMIC_RELAXED,
                           __HIP_MEMORY_SCOPE_AGENT);
    while (__hip_atomic_load(cnt, __ATOMIC_RELAXED,
                             __HIP_MEMORY_SCOPE_AGENT) < target)
      __builtin_amdgcn_s_sleep(1);
  }
  __syncthreads();
}

// ---------------------------------------------------------------------------
// Main persistent kernel: 256 blocks x 512 thr (8 waves, 1 block/CU) — the
// round-6 champion shape, minus the lo plane. Block (rg=bx&15, cb=bx>>4):
// rows [rg*16,+16), h-cols [cb*64,+64). Wave w: jp=w&3 (jg=cb*4+jp),
// kh=w>>2 (K-half); bW = 48 chunks. Coherent-fabric staging: 8 MB/step
// (was 16) — rounds 4/5/6 established step time tracks staged bytes;
// round 8 (AGPR-resident bW) established W-residency is NOT the binder.
// ---------------------------------------------------------------------------
__global__ __launch_bounds__(512, 2) void gru_main(
    const float* __restrict__ x,
    const float* __restrict__ bih_e, const float* __restrict__ bhh_e,
    const float* __restrict__ Wih_d,
    const float* __restrict__ bih_d, const float* __restrict__ bhh_d,
    const float* __restrict__ fcW, const float* __restrict__ fcb,
    float* __restrict__ out, char* __restrict__ ws) {

  __shared__ __align__(128) char atile[32768];  // [kb 32][L 64][16B]
  __shared__ float red[4 * 64 * 17];            // kh1 partials [jp][L][17]
  __shared__ __align__(16) char otile[2048];    // h' image (2KB)
  __shared__ float inp_lds[16];

  const int tid = threadIdx.x;
  const int L = tid & 63;
  const int w = tid >> 6;
  const int jp = w & 3;
  const int kh = w >> 2;
  const int bx = blockIdx.x;
  const int rg = bx & 15;
  const int cb = bx >> 4;
  const int r = L & 15;
  const int q = L >> 4;
  const int jg = cb * 4 + jp;
  const int jc = jg * 16 + r;

  unsigned int* bar = (unsigned int*)(ws + BARS) + (size_t)rg * 32;
  unsigned int bt = 0;

  const size_t slab = (size_t)rg * 32768;

  // zero own h'-region of parity 0 (2KB/block)
  if (tid < 256) {
    sta8(ws + HP + slab + (size_t)cb * 2048 + (size_t)tid * 8, 0ull);
  }

  float hold[4] = {0.f, 0.f, 0.f, 0.f};
  const float fcb_s = *fcb;
  const float fcw_l = fcW[jc];

  bt += 16;
  gbar(bar, bt);

  for (int phase = 0; phase < 2; ++phase) {
    // register-resident W_hh B-frags for (jg, kh): [gate][kk].
    half8 bW[48];
    {
      const char* wf = ws + (phase ? WF_D : WF_E);
#pragma unroll
      for (int g = 0; g < 3; ++g)
#pragma unroll
        for (int kk = 0; kk < 16; ++kk)
          bW[g * 16 + kk] = *(const half8*)(
              wf + (size_t)((g * 64 + jg) * 32 + kh * 16 + kk) * 1024 +
              (size_t)L * 16);
#pragma unroll
      for (int i = 0; i < 48; ++i) asm volatile("" : "+v"(bW[i]));
    }
    const float* bih = phase ? bih_d : bih_e;
    const float* bhh = phase ? bhh_d : bhh_e;
    const float b_r  = bih[jc]          + bhh[jc];
    const float b_z  = bih[H_ + jc]     + bhh[H_ + jc];
    const float b_in = bih[2 * H_ + jc];
    const float b_hn = bhh[2 * H_ + jc];
    float wd_r = 0.f, wd_z = 0.f, wd_n = 0.f;
    if (phase) {
      wd_r = Wih_d[jc]; wd_z = Wih_d[H_ + jc]; wd_n = Wih_d[2 * H_ + jc];
    }

    const int nsteps = phase ? TL_ : T_;
    for (int d = 0; d < nsteps; ++d) {
      const int s = phase ? T_ + d : d;

      // ---- stage A slab (32KB) via async global->LDS DMA, LLC-coherent
      //      (aux 17 = sc0|sc1). 32 segs of 1KB; wave w takes segs
      //      w*4..w*4+3; lane L's 16B lands at seg base + L*16. ----
      {
        const char* srcbase = ws + HP + (size_t)(s & 1) * PSTR + slab;
#pragma unroll
        for (int c = 0; c < 4; ++c) {
          const int seg = w * 4 + c;  // 0..31
          const char* src = srcbase + (size_t)seg * 1024 + (size_t)L * 16;
          __builtin_amdgcn_global_load_lds(
              (const __attribute__((address_space(1))) void*)src,
              (__attribute__((address_space(3))) void*)(atile + seg * 1024),
              16, 0, 17);
        }
      }

      // ---- decoder scalar input (overlaps the staging DMA) ----
      if (phase && tid < 16) {
        float sum = 0.f;
        if (d > 0) {
          const float* pb =
              (const float*)(ws + PB) + (size_t)((d + 1) & 1) * 64 * 256;
          int row = rg * 16 + tid;
          float a = fcb_s;
          for (int jj = 0; jj < 64; ++jj) a += lda4f(&pb[jj * 256 + row]);
          sum = a;
          if (cb == 0) out[(size_t)row * TL_ + (d - 1)] = a;
        }
        inp_lds[tid] = sum;
      }
      __syncthreads();  // drains vmcnt -> DMA complete

      floatx4 a0 = {0.f, 0.f, 0.f, 0.f}, a1 = {0.f, 0.f, 0.f, 0.f};
      floatx4 a2 = {0.f, 0.f, 0.f, 0.f}, aI = {0.f, 0.f, 0.f, 0.f};

      // ---- h-GEMM, this wave's K-half (stride-1 ds_read_b128) ----
#pragma unroll
      for (int kk = 0; kk < 16; ++kk) {
        const int kb = kh * 16 + kk;
        half8 ahi = *(const half8*)(atile + kb * 1024 + L * 16);
        a0 = MFMA(ahi, bW[kk], a0);
        a1 = MFMA(ahi, bW[16 + kk], a1);
        a2 = MFMA(ahi, bW[32 + kk], a2);
      }

      // ---- kh1: encoder x-projection + dump partials ----
      if (kh == 1) {
        if (!phase) {
          const float* xp =
              x + ((size_t)(rg * 16 + r) * T_ + s) * F_ + q * 8;
          const char* wfi = ws + WF_I + (size_t)L * 16;  // L1/L2-hot reloads
#pragma unroll
          for (int kc = 0; kc < 2; ++kc) {
            floatx4 x0 = *(const floatx4*)(xp + kc * 32);
            floatx4 x1 = *(const floatx4*)(xp + kc * 32 + 4);
            half8 xa;
#pragma unroll
            for (int i = 0; i < 4; ++i) {
              xa[i] = (_Float16)x0[i];
              xa[4 + i] = (_Float16)x1[i];
            }
            a0 = MFMA(xa, *(const half8*)(wfi +
                     (size_t)((0 * 64 + jg) * 2 + kc) * 1024), a0);
            a1 = MFMA(xa, *(const half8*)(wfi +
                     (size_t)((1 * 64 + jg) * 2 + kc) * 1024), a1);
            aI = MFMA(xa, *(const half8*)(wfi +
                     (size_t)((2 * 64 + jg) * 2 + kc) * 1024), aI);
          }
        }
        float* rd = &red[(jp * 64 + L) * 17];
#pragma unroll
        for (int i = 0; i < 4; ++i) {
          rd[i] = a0[i];
          rd[4 + i] = a1[i];
          rd[8 + i] = a2[i];
        }
        if (!phase) {
#pragma unroll
          for (int i = 0; i < 4; ++i) rd[12 + i] = aI[i];
        }
      }
      __syncthreads();

      // ---- kh0: reduce halves, gate epilogue, h' -> otile ----
      if (kh == 0) {
        const float* rd = &red[(jp * 64 + L) * 17];
        const size_t tbase = (size_t)(jp >> 1) * 1024 +
                             (size_t)((jp & 1) * 2 + (r >> 3)) * 256 +
                             (size_t)(r & 7) * 2;
        float pv[4];
#pragma unroll
        for (int i = 0; i < 4; ++i) {
          float rpre = a0[i] + rd[i] + b_r;
          float zpre = a1[i] + rd[4 + i] + b_z;
          float hn   = a2[i] + rd[8 + i] + b_hn;
          float inn  = b_in + (phase ? 0.f : rd[12 + i]);
          if (phase) {
            float inp = inp_lds[q * 4 + i];
            rpre += inp * wd_r;
            zpre += inp * wd_z;
            inn  += inp * wd_n;
          }
          float rg_ = 1.f / (1.f + __expf(-rpre));
          float zg = 1.f / (1.f + __expf(-zpre));
          float t2 = __expf(-2.f * (inn + rg_ * hn));
          float ng = 2.f / (1.f + t2) - 1.f;  // tanh, safe at +-inf
          float hnew = (1.f - zg) * ng + zg * hold[i];
          hold[i] = hnew;  // fp32 carry: storage quant never compounds here
          *(_Float16*)(otile + tbase + (size_t)(q * 4 + i) * 16) =
              (_Float16)hnew;
          pv[i] = hnew * fcw_l;
        }
        if (phase) {
#pragma unroll
          for (int i = 0; i < 4; ++i) {
            float v = pv[i];
            v += __shfl_xor(v, 1);
            v += __shfl_xor(v, 2);
            v += __shfl_xor(v, 4);
            v += __shfl_xor(v, 8);
            if (r == 0) {
              float* pb = (float*)(ws + PB) + (size_t)(d & 1) * 64 * 256;
              __hip_atomic_store(&pb[jg * 256 + (rg * 16 + q * 4 + i)], v,
                                 __ATOMIC_RELAXED, __HIP_MEMORY_SCOPE_AGENT);
            }
          }
        }
      }
      __syncthreads();

      // ---- stream h' (2KB) out: coalesced 8B LLC stores ----
      if (tid < 256) {
        ull v = *(const ull*)(otile + (size_t)tid * 8);
        sta8(ws + HP + (size_t)((s + 1) & 1) * PSTR + slab +
                 (size_t)cb * 2048 + (size_t)tid * 8,
             v);
      }

      bt += 16;
      gbar(bar, bt);
    }
  }

  // ---- final output column t = TL-1 ----
  if (cb == 0 && tid < 16) {
    const float* pb =
        (const float*)(ws + PB) + (size_t)((TL_ - 1) & 1) * 64 * 256;
    int row = rg * 16 + tid;
    float a = fcb_s;
    for (int jj = 0; jj < 64; ++jj) a += lda4f(&pb[jj * 256 + row]);
    out[(size_t)row * TL_ + (TL_ - 1)] = a;
  }
}

// ---------------------------------------------------------------------------
extern "C" void kernel_launch(void* const* d_in, const int* in_sizes, int n_in,
                              void* d_out, int out_size, void* d_ws,
                              size_t ws_size, hipStream_t stream) {
  const float* x     = (const float*)d_in[0];
  const float* WihE  = (const float*)d_in[1];
  const float* WhhE  = (const float*)d_in[2];
  const float* bihE  = (const float*)d_in[3];
  const float* bhhE  = (const float*)d_in[4];
  const float* WihD  = (const float*)d_in[5];
  const float* WhhD  = (const float*)d_in[6];
  const float* bihD  = (const float*)d_in[7];
  const float* bhhD  = (const float*)d_in[8];
  const float* fcW   = (const float*)d_in[9];
  const float* fcb   = (const float*)d_in[10];
  float* outp = (float*)d_out;
  char* ws = (char*)d_ws;

  gru_setup<<<3168, 256, 0, stream>>>(WhhE, WhhD, WihE, ws);

  gru_main<<<dim3(256), dim3(512), 0, stream>>>(
      x, bihE, bhhE, WihD, bihD, bhhD, fcW, fcb, outp, ws);
}